// Round 1
// baseline (67517.493 us; speedup 1.0000x reference)
//
#include <hip/hip_runtime.h>
#include <hip/hip_bf16.h>
#include <math.h>

#define EPSV 1e-5f
#define BDIM 32
#define TSTEPS 2048
#define DIN 256
#define HDIM 512
#define H2 1024
#define H3 1536

// ---------------- fp32 tiled GEMM: C = A(MxK) @ B(KxN) (+bias) ----------------
template <int BM, int BN, int BK, int TM, int TN>
__global__ __launch_bounds__(256) void sgemm(const float* __restrict__ A,
                                             const float* __restrict__ B,
                                             const float* __restrict__ bias,
                                             float* __restrict__ C,
                                             int M, int N, int K) {
    __shared__ float As[BK][BM + 4];
    __shared__ float Bs[BK][BN + 4];

    const int tid = threadIdx.x;
    const int bm = blockIdx.y * BM;
    const int bn = blockIdx.x * BN;

    const int tr = (tid >> 4) * TM;  // 0..120 step 8
    const int tc = (tid & 15) * TN;

    float acc[TM][TN];
#pragma unroll
    for (int i = 0; i < TM; ++i)
#pragma unroll
        for (int j = 0; j < TN; ++j) acc[i][j] = 0.f;

    for (int k0 = 0; k0 < K; k0 += BK) {
        // load A tile (BM x BK), 512 float4s, 2 per thread
#pragma unroll
        for (int r = 0; r < 2; ++r) {
            int f = tid + r * 256;
            int arow = f >> 2;          // 0..127
            int acol = (f & 3) * 4;     // 0,4,8,12
            float4 v = *(const float4*)&A[(size_t)(bm + arow) * K + k0 + acol];
            As[acol + 0][arow] = v.x;
            As[acol + 1][arow] = v.y;
            As[acol + 2][arow] = v.z;
            As[acol + 3][arow] = v.w;
        }
        // load B tile (BK x BN)
#pragma unroll
        for (int r = 0; r < 2; ++r) {
            int f = tid + r * 256;
            int brow = f >> 5;          // 0..15
            int bcol = (f & 31) * 4;    // 0..124
            float4 v = *(const float4*)&B[(size_t)(k0 + brow) * N + bn + bcol];
            *(float4*)&Bs[brow][bcol] = v;
        }
        __syncthreads();
#pragma unroll
        for (int k = 0; k < BK; ++k) {
            float a[TM], b[TN];
            float4 a0 = *(const float4*)&As[k][tr];
            float4 a1 = *(const float4*)&As[k][tr + 4];
            a[0] = a0.x; a[1] = a0.y; a[2] = a0.z; a[3] = a0.w;
            a[4] = a1.x; a[5] = a1.y; a[6] = a1.z; a[7] = a1.w;
            float4 b0 = *(const float4*)&Bs[k][tc];
            float4 b1 = *(const float4*)&Bs[k][tc + 4];
            b[0] = b0.x; b[1] = b0.y; b[2] = b0.z; b[3] = b0.w;
            b[4] = b1.x; b[5] = b1.y; b[6] = b1.z; b[7] = b1.w;
#pragma unroll
            for (int i = 0; i < TM; ++i)
#pragma unroll
                for (int j = 0; j < TN; ++j) acc[i][j] += a[i] * b[j];
        }
        __syncthreads();
    }

#pragma unroll
    for (int i = 0; i < TM; ++i) {
        size_t row = (size_t)(bm + tr + i) * N + bn + tc;
#pragma unroll
        for (int j = 0; j < TN; j += 4) {
            float4 o;
            o.x = acc[i][j + 0];
            o.y = acc[i][j + 1];
            o.z = acc[i][j + 2];
            o.w = acc[i][j + 3];
            if (bias) {
                o.x += bias[bn + tc + j + 0];
                o.y += bias[bn + tc + j + 1];
                o.z += bias[bn + tc + j + 2];
                o.w += bias[bn + tc + j + 3];
            }
            *(float4*)&C[row + j] = o;
        }
    }
}

// ---------------- block-wide {sum, sumsq} reduction (256 threads) -------------
__device__ __forceinline__ void block_reduce2(float& a, float& b, float* red) {
#pragma unroll
    for (int off = 32; off > 0; off >>= 1) {
        a += __shfl_down(a, off);
        b += __shfl_down(b, off);
    }
    const int wid = threadIdx.x >> 6;
    __syncthreads();  // protect red[] from previous round's readers
    if ((threadIdx.x & 63) == 0) {
        red[wid] = a;
        red[4 + wid] = b;
    }
    __syncthreads();
    a = red[0] + red[1] + red[2] + red[3];
    b = red[4] + red[5] + red[6] + red[7];
}

// ---------------- recurrent scan: one block per batch row --------------------
__global__ __launch_bounds__(256) void scan_kernel(
    const float* __restrict__ s1raw,   // (B, T, 3H) raw (x_emb@W), no bias/LN yet
    const float* __restrict__ U,       // (H, 3H)
    const float* __restrict__ bias,    // (3H,)
    const float* __restrict__ gammas,  // (2, 3H)
    const float* __restrict__ betas,   // (2, 3H)
    const int* __restrict__ mask,      // (B, T)
    float* __restrict__ out)           // (B, T, H)
{
    const int bb = blockIdx.x;
    const int tid = threadIdx.x;

    __shared__ float h_s[HDIM];
    __shared__ float s1_s[H3];
    __shared__ float rh_s[HDIM];
    __shared__ float z_s[HDIM];
    __shared__ float g0_s[H3], bt0_s[H3], g1_s[H3], bt1_s[H3], bias_s[H3];
    __shared__ float red[8];

    for (int k = tid; k < H3; k += 256) {
        g0_s[k] = gammas[k];
        bt0_s[k] = betas[k];
        g1_s[k] = gammas[H3 + k];
        bt1_s[k] = betas[H3 + k];
        bias_s[k] = bias[k];
    }
    for (int k = tid; k < HDIM; k += 256) h_s[k] = 0.f;
    __syncthreads();

    const float* s1row = s1raw + (size_t)bb * TSTEPS * H3;
    const int* mrow = mask + bb * TSTEPS;
    float* orow = out + (size_t)bb * TSTEPS * HDIM;

    for (int t = 0; t < TSTEPS; ++t) {
        // ---- LN0 over the 3H s1 row (bias + layernorm with gammas[0]) ----
        float v[6];
        float sum = 0.f, ssq = 0.f;
#pragma unroll
        for (int j = 0; j < 6; ++j) {
            int k = tid + j * 256;
            float x = s1row[k] + bias_s[k];
            v[j] = x;
            sum += x;
            ssq += x * x;
        }
        block_reduce2(sum, ssq, red);
        {
            float m = sum * (1.f / H3);
            float var = fmaxf(ssq * (1.f / H3) - m * m, 0.f);
            float inv = 1.f / (sqrtf(var + EPSV) + EPSV);
#pragma unroll
            for (int j = 0; j < 6; ++j) {
                int k = tid + j * 256;
                s1_s[k] = g0_s[k] * ((v[j] - m) * inv) + bt0_s[k];
            }
        }
        __syncthreads();

        // ---- GEMV1: tmp_zr = h @ U_zr (cols 0..1023), 4 cols/thread ----
        float a0 = 0.f, a1 = 0.f, a2 = 0.f, a3 = 0.f;
        {
            const float* Up = U + 4 * tid;
#pragma unroll 8
            for (int i = 0; i < HDIM; ++i) {
                float hv = h_s[i];
                float4 u = *(const float4*)(Up + (size_t)i * H3);
                a0 += hv * u.x;
                a1 += hv * u.y;
                a2 += hv * u.z;
                a3 += hv * u.w;
            }
        }
        sum = a0 + a1 + a2 + a3;
        ssq = a0 * a0 + a1 * a1 + a2 * a2 + a3 * a3;
        block_reduce2(sum, ssq, red);
        {
            float m = sum * (1.f / H2);
            float var = fmaxf(ssq * (1.f / H2) - m * m, 0.f);
            float inv = 1.f / (sqrtf(var + EPSV) + EPSV);
            float sv[4] = {a0, a1, a2, a3};
#pragma unroll
            for (int j = 0; j < 4; ++j) {
                int k = 4 * tid + j;  // 0..1023
                float s2 = g1_s[k] * ((sv[j] - m) * inv) + bt1_s[k];
                float pre = s1_s[k] + s2;
                float s = fminf(fmaxf(0.2f * pre + 0.5f, 0.f), 1.f);
                if (k < HDIM)
                    z_s[k] = s;
                else
                    rh_s[k - HDIM] = s * h_s[k - HDIM];
            }
        }
        __syncthreads();

        // ---- GEMV2: tmp_h = (r*h) @ U_h (cols 1024..1535), 2 cols/thread ----
        float c0 = 0.f, c1 = 0.f;
        {
            const float* Uh = U + H2 + 2 * tid;
#pragma unroll 8
            for (int i = 0; i < HDIM; ++i) {
                float rv = rh_s[i];
                float2 u = *(const float2*)(Uh + (size_t)i * H3);
                c0 += rv * u.x;
                c1 += rv * u.y;
            }
        }
        sum = c0 + c1;
        ssq = c0 * c0 + c1 * c1;
        block_reduce2(sum, ssq, red);
        {
            float m = sum * (1.f / HDIM);
            float var = fmaxf(ssq * (1.f / HDIM) - m * m, 0.f);
            float inv = 1.f / (sqrtf(var + EPSV) + EPSV);
            const bool mb = (mrow[t] != 0);
            float hn[2];
#pragma unroll
            for (int j = 0; j < 2; ++j) {
                int c = 2 * tid + j;
                float acc = (j == 0) ? c0 : c1;
                float ln = g1_s[H2 + c] * ((acc - m) * inv) + bt1_s[H2 + c];
                float hc = tanhf(s1_s[H2 + c] + ln);
                float hp = h_s[c];
                float z = z_s[c];
                float h_ = z * hp + (1.f - z) * hc;
                hn[j] = mb ? h_ : hp;
                h_s[c] = hn[j];
            }
            float2 o;
            o.x = hn[0];
            o.y = hn[1];
            *(float2*)&orow[(size_t)t * HDIM + 2 * tid] = o;
        }
        __syncthreads();  // h_s complete before next step's GEMV1
        s1row += H3;
    }
}

extern "C" void kernel_launch(void* const* d_in, const int* in_sizes, int n_in,
                              void* d_out, int out_size, void* d_ws, size_t ws_size,
                              hipStream_t stream) {
    const float* x      = (const float*)d_in[0];
    const int*   mask   = (const int*)d_in[1];
    const float* W_emb  = (const float*)d_in[2];
    const float* b_emb  = (const float*)d_in[3];
    const float* W      = (const float*)d_in[4];
    const float* U      = (const float*)d_in[5];
    const float* bias   = (const float*)d_in[6];
    const float* gammas = (const float*)d_in[7];
    const float* betas  = (const float*)d_in[8];
    float* out = (float*)d_out;

    const int M = BDIM * TSTEPS;  // 65536
    float* x_emb = (float*)d_ws;                      // M x 512  (128 MB)
    float* s1raw = x_emb + (size_t)M * HDIM;          // M x 1536 (384 MB)

    // x_emb = x @ W_emb + b_emb
    sgemm<128, 128, 16, 8, 8><<<dim3(HDIM / 128, M / 128), 256, 0, stream>>>(
        x, W_emb, b_emb, x_emb, M, HDIM, DIN);
    // s1raw = x_emb @ W   (bias + LN fused into scan)
    sgemm<128, 128, 16, 8, 8><<<dim3(H3 / 128, M / 128), 256, 0, stream>>>(
        x_emb, W, nullptr, s1raw, M, H3, HDIM);
    // recurrent scan, one block per batch row
    scan_kernel<<<BDIM, 256, 0, stream>>>(s1raw, U, bias, gammas, betas, mask, out);
}